// Round 16
// baseline (192.821 us; speedup 1.0000x reference)
//
#include <hip/hip_runtime.h>

// ---------- types ----------
typedef unsigned short u16;
typedef __bf16 bf16x8 __attribute__((ext_vector_type(8)));
typedef float f32x4 __attribute__((ext_vector_type(4)));
typedef unsigned short u16x8 __attribute__((ext_vector_type(8)));

#define VM_WAIT(N) asm volatile("s_waitcnt vmcnt(" #N ")" ::: "memory")

__device__ __forceinline__ u16 f2bf(float f) {
    union { float f; unsigned int u; } v; v.f = f;
    unsigned int r = v.u + 0x7fffu + ((v.u >> 16) & 1u);
    return (u16)(r >> 16);
}
__device__ __forceinline__ float bf2f(u16 h) {
    union { unsigned int u; float f; } v; v.u = ((unsigned int)h) << 16;
    return v.f;
}

__device__ __forceinline__ void gld_lds16(const void* g, void* l) {
    __builtin_amdgcn_global_load_lds(
        (const __attribute__((address_space(1))) void*)g,
        (__attribute__((address_space(3))) void*)l, 16, 0, 0);
}

// ---------- fused f32 -> bf16 cast of 3 tensors (x, Wq, Wkv) ----------
__global__ __launch_bounds__(256) void cvt3(const float* __restrict__ s0, u16* __restrict__ d0, int n0,
                                            const float* __restrict__ s1, u16* __restrict__ d1, int n1,
                                            const float* __restrict__ s2, u16* __restrict__ d2, int n2) {
    int total = n0 + n1 + n2;
    for (int i = blockIdx.x * 256 + threadIdx.x; i < total; i += gridDim.x * 256) {
        const float* s; u16* o; int j = i;
        if (j < n0) { s = s0; o = d0; }
        else if ((j -= n0) < n1) { s = s1; o = d1; }
        else { j -= n1; s = s2; o = d2; }
        float4 v = reinterpret_cast<const float4*>(s)[j];
        ushort4 u;
        u.x = f2bf(v.x); u.y = f2bf(v.y); u.z = f2bf(v.z); u.w = f2bf(v.w);
        reinterpret_cast<ushort4*>(o)[j] = u;
    }
}

// ---------- deep-pipelined GEMM, parametrized tile ----------
// BM=256 -> 512 thr, 2x4 waves ; BM=128 -> 256 thr, 2x2 waves (2 blocks/CU).
// MODE 0: C f32 out. MODE 1 (256x256, QKV): swapped mfma + fused rope/vt epilogue;
//         blocks with swz>=192 instead cast Wo f32->bf16 (rides the idle CUs).
template <int BM, int BN, int MODE>
__global__ __launch_bounds__((BM == 256) ? 512 : 256, 2)
void gemm_dp(const u16* __restrict__ Amat,
             const u16* __restrict__ B1,
             const u16* __restrict__ B2,
             const float* __restrict__ bias1,
             const float* __restrict__ bias2,
             float* __restrict__ Cout,
             const float* __restrict__ cosb,
             const float* __restrict__ sinb,
             u16* __restrict__ qb,
             u16* __restrict__ kb,
             u16* __restrict__ vtb,
             const float* __restrict__ wof,
             u16* __restrict__ wobf,
             int M, int N, int K, int NS, int nbn) {
    constexpr int THREADS = (BM == 256) ? 512 : 256;
    constexpr int WN = (BM == 256) ? 4 : 2;       // waves along N
    constexpr int WNS = (BM == 256) ? 2 : 1;      // log2(WN)
    constexpr int MF = BM / 32;                   // per-wave m-frags (BM/2/16)
    constexpr int NR = BN / (WN * 16);            // per-wave n-frags
    constexpr int RPI = THREADS / 4;              // rows per staging instr
    constexpr int SA = BM / RPI;
    constexpr int SB = BN / RPI;
    __shared__ __align__(16) u16 lds[2][(BM + BN) * 64];

    const int tid = threadIdx.x;
    const int lane = tid & 63;
    const int wid = tid >> 6;
    const int l15 = lane & 15, kl = lane >> 4;
    const int wm = wid >> WNS, wn = wid & (WN - 1);

    const int nwg = gridDim.x;
    const int cpx = nwg >> 3;
    const int bidr = blockIdx.x;
    const int swz = (bidr & 7) * cpx + (bidr >> 3);

    if constexpr (MODE == 1) {
        // extra blocks (swz >= nbn*M/BM = 192) cast Wo while GEMM runs elsewhere
        if (swz >= 192) {
            int idx = swz - 192;                           // 0..63
            const float4* src = reinterpret_cast<const float4*>(wof);
            for (int i = idx * THREADS + tid; i < 2048 * 2048 / 4; i += 64 * THREADS) {
                float4 v = src[i];
                ushort4 u;
                u.x = f2bf(v.x); u.y = f2bf(v.y); u.z = f2bf(v.z); u.w = f2bf(v.w);
                reinterpret_cast<ushort4*>(wobf)[i] = u;
            }
            return;
        }
    }

    const int bm = swz / nbn, bn = swz % nbn;

    const int r0 = tid >> 2, c0 = tid & 3;

    const u16* agp[SA];
#pragma unroll
    for (int i = 0; i < SA; ++i) {
        int row = i * RPI + r0;
        agp[i] = Amat + (long)(bm * BM + row) * K + ((c0 ^ ((row >> 1) & 3)) * 8);
    }
    const u16* bgp[SB];
#pragma unroll
    for (int i = 0; i < SB; ++i) {
        int row = i * RPI + r0;
        int nrow = bn * BN + row;
        const u16* base = (nrow < NS) ? (B1 + (long)nrow * K) : (B2 + (long)(nrow - NS) * K);
        bgp[i] = base + ((c0 ^ ((row >> 1) & 3)) * 8);
    }

    auto STAGE_A = [&](int db, int kt, int kh) {
#pragma unroll
        for (int i = 0; i < SA; ++i)
            gld_lds16(agp[i] + kt * 64 + kh * 32,
                      &lds[db][kh * (BM * 32) + i * (RPI * 32) + tid * 8]);
    };
    auto STAGE_B = [&](int db, int kt, int kh) {
#pragma unroll
        for (int i = 0; i < SB; ++i)
            gld_lds16(bgp[i] + kt * 64 + kh * 32,
                      &lds[db][BM * 64 + kh * (BN * 32) + i * (RPI * 32) + tid * 8]);
    };

    f32x4 acc[MF][NR] = {};

#define PHASE(DB, KS, DOSTAGE, DOWAIT)                                                  \
    {                                                                                   \
        bf16x8 af[MF], bfr[NR];                                                         \
        _Pragma("unroll")                                                               \
        for (int i = 0; i < MF; ++i) {                                                  \
            int row = wm * (BM / 2) + i * 16 + l15;                                     \
            af[i] = *reinterpret_cast<const bf16x8*>(                                   \
                &lds[DB][(KS) * (BM * 32) + row * 32 + ((kl ^ ((row >> 1) & 3)) * 8)]); \
        }                                                                               \
        _Pragma("unroll")                                                               \
        for (int n = 0; n < NR; ++n) {                                                  \
            int brow = wn * (BN / WN) + n * 16 + l15;                                   \
            bfr[n] = *reinterpret_cast<const bf16x8*>(                                  \
                &lds[DB][BM * 64 + (KS) * (BN * 32) + brow * 32 +                       \
                         ((kl ^ ((brow >> 1) & 3)) * 8)]);                              \
        }                                                                               \
        DOSTAGE;                                                                        \
        DOWAIT;                                                                         \
        __builtin_amdgcn_s_barrier();                                                   \
        __builtin_amdgcn_s_setprio(1);                                                  \
        _Pragma("unroll")                                                               \
        for (int i = 0; i < MF; ++i)                                                    \
            _Pragma("unroll")                                                           \
            for (int n = 0; n < NR; ++n) {                                              \
                if constexpr (MODE == 1)                                                \
                    acc[i][n] = __builtin_amdgcn_mfma_f32_16x16x32_bf16(                \
                        bfr[n], af[i], acc[i][n], 0, 0, 0);                             \
                else                                                                    \
                    acc[i][n] = __builtin_amdgcn_mfma_f32_16x16x32_bf16(                \
                        af[i], bfr[n], acc[i][n], 0, 0, 0);                             \
            }                                                                           \
        __builtin_amdgcn_s_setprio(0);                                                  \
    }

    STAGE_A(0, 0, 0); STAGE_B(0, 0, 0); STAGE_A(0, 0, 1); STAGE_B(0, 0, 1);
    VM_WAIT(4);
    __builtin_amdgcn_s_barrier();

    const int NT = K >> 6;
    for (int t = 0; t < NT; ++t) {
        const int db = t & 1;
        const bool pre = (t + 1) < NT;
        const int kt1 = t + 1;
        PHASE(db, 0, { if (pre) { STAGE_A(db ^ 1, kt1, 0); STAGE_B(db ^ 1, kt1, 0); } },
              { if (pre) VM_WAIT(4); else VM_WAIT(0); });
        PHASE(db, 1, { if (pre) { STAGE_A(db ^ 1, kt1, 1); STAGE_B(db ^ 1, kt1, 1); } },
              { if (pre) VM_WAIT(4); else VM_WAIT(0); });
    }
#undef PHASE

    if constexpr (MODE == 0) {
#pragma unroll
        for (int n = 0; n < NR; ++n) {
            int col = bn * BN + wn * (BN / WN) + n * 16 + l15;
            float bv = 0.f;
            if (bias1) bv = (col < NS) ? bias1[col] : bias2[col - NS];
#pragma unroll
            for (int m = 0; m < MF; ++m) {
                int row = bm * BM + wm * (BM / 2) + m * 16 + kl * 4;
                float* cp = Cout + (long)row * N + col;
#pragma unroll
                for (int j = 0; j < 4; ++j) cp[(long)j * N] = acc[m][n][j] + bv;
            }
        }
    } else {
        // ---- fused QKV epilogue (BM=256/512thr only) ----
        const float SCALE = 0.08838834764831845f; // 1/sqrt(128)
        const int T = 2048;
        __syncthreads();
        char* otb = reinterpret_cast<char*>(lds);
#pragma unroll
        for (int n = 0; n < NR; ++n) {
            int cbase = wn * 64 + n * 16 + kl * 4;
            int col = bn * BN + cbase;
            const float* bsrc = (col < NS) ? (bias1 + col) : (bias2 + col - NS);
            float4 bv4 = *reinterpret_cast<const float4*>(bsrc);
#pragma unroll
            for (int i = 0; i < MF; ++i) {
                int lrow = wm * 128 + i * 16 + l15;
                ushort4 pk;
                pk.x = f2bf(acc[i][n][0] + bv4.x);
                pk.y = f2bf(acc[i][n][1] + bv4.y);
                pk.z = f2bf(acc[i][n][2] + bv4.z);
                pk.w = f2bf(acc[i][n][3] + bv4.w);
                int byteoff = lrow * 512 + ((((cbase >> 3) ^ (lrow & 31)) << 4) +
                                            ((cbase & 7) << 1));
                *reinterpret_cast<ushort4*>(otb + byteoff) = pk;
            }
        }
        __syncthreads();

        const int R0 = bm * BM;
        const int bb = R0 >> 11;
        const int t0 = R0 & 2047;

        if (bn < 8) {
            int r = tid >> 1, side = tid & 1;
            int h = bn * 2 + side, tt = t0 + r;
            const float* cr = cosb + tt * 128;
            const float* sr = sinb + tt * 128;
            const char* srcr = otb + r * 512;
            int rx = r & 31;
            u16* dst = qb + ((long)(bb * 16 + h) * T + tt) * 128;
#pragma unroll
            for (int d0 = 0; d0 < 64; d0 += 8) {
                u16x8 a = *reinterpret_cast<const u16x8*>(
                    srcr + (((side * 16 + (d0 >> 3)) ^ rx) << 4));
                u16x8 bvv = *reinterpret_cast<const u16x8*>(
                    srcr + (((side * 16 + 8 + (d0 >> 3)) ^ rx) << 4));
                u16x8 o1, o2;
#pragma unroll
                for (int j = 0; j < 8; ++j) {
                    float q1 = bf2f(a[j]), q2 = bf2f(bvv[j]);
                    o1[j] = f2bf((q1 * cr[d0 + j] - q2 * sr[d0 + j]) * SCALE);
                    o2[j] = f2bf((q2 * cr[64 + d0 + j] + q1 * sr[64 + d0 + j]) * SCALE);
                }
                *reinterpret_cast<u16x8*>(dst + d0) = o1;
                *reinterpret_cast<u16x8*>(dst + 64 + d0) = o2;
            }
        } else if (bn < 10) {
            int r = tid >> 1, side = tid & 1;
            int g = (bn - 8) * 2 + side, tt = t0 + r;
            const float* cr = cosb + tt * 128;
            const float* sr = sinb + tt * 128;
            const char* srcr = otb + r * 512;
            int rx = r & 31;
            u16* dst = kb + ((long)(bb * 4 + g) * T + tt) * 128;
#pragma unroll
            for (int d0 = 0; d0 < 64; d0 += 8) {
                u16x8 a = *reinterpret_cast<const u16x8*>(
                    srcr + (((side * 16 + (d0 >> 3)) ^ rx) << 4));
                u16x8 bvv = *reinterpret_cast<const u16x8*>(
                    srcr + (((side * 16 + 8 + (d0 >> 3)) ^ rx) << 4));
                u16x8 o1, o2;
#pragma unroll
                for (int j = 0; j < 8; ++j) {
                    float k1 = bf2f(a[j]), k2 = bf2f(bvv[j]);
                    o1[j] = f2bf(k1 * cr[d0 + j] - k2 * sr[d0 + j]);
                    o2[j] = f2bf(k2 * cr[64 + d0 + j] + k1 * sr[64 + d0 + j]);
                }
                *reinterpret_cast<u16x8*>(dst + d0) = o1;
                *reinterpret_cast<u16x8*>(dst + 64 + d0) = o2;
            }
        } else {
            int cl = tid >> 1, th = tid & 1;
            int side = cl >> 7, d = cl & 127;
            int g = (bn - 10) * 2 + side;
            u16* dst = vtb + ((long)(bb * 4 + g) * 128 + d) * T + t0 + th * 128;
            int cch = cl >> 3, coff = (cl & 7) << 1;
#pragma unroll
            for (int i0 = 0; i0 < 128; i0 += 8) {
                u16 tmp[8];
#pragma unroll
                for (int i = 0; i < 8; ++i) {
                    int row = th * 128 + i0 + i;
                    tmp[i] = *reinterpret_cast<const u16*>(
                        otb + row * 512 + (((cch ^ (row & 31)) << 4) + coff));
                }
                *reinterpret_cast<uint4*>(dst + i0) = *reinterpret_cast<const uint4*>(tmp);
            }
        }
    }
}

// ---------- flash attention, causal GQA (R8 structure + XCD-clustered bid) ----------
__global__ __launch_bounds__(256, 2) void attn_fwd(const u16* __restrict__ qb,
                                                   const u16* __restrict__ kb,
                                                   const u16* __restrict__ vtb,
                                                   u16* __restrict__ ob) {
    const int T = 2048;
    __shared__ __align__(16) u16 Ks[2][64 * 128];   // [buf][key][d], XOR-swizzled
    __shared__ __align__(16) u16 Vs[2][128 * 64];   // [buf][d][key], XOR-swizzled
    __shared__ __align__(16) u16 Ps[4][16 * 64];    // per-wave P^ [q][key], XOR-swizzled

    const int tid = threadIdx.x;
    const int lane = tid & 63;
    const int w = tid >> 6;
    const int l15 = lane & 15, kl = lane >> 4;
    const int bid = blockIdx.x;                     // 512 ; bid&7 == b*4+g -> one (b,g)/XCD
    const int g = bid & 3;
    const int b = (bid >> 2) & 1;
    const int jp = (bid >> 3) & 15;
    const int hh = (bid >> 7) & 3;
    const int h = g * 4 + hh;
    const int jlo = jp, jhi = 31 - jp;              // paired Q-tiles: work = 33 everywhere

    bf16x8 qlo[4], qhi[4];
    {
        const u16* qbase = qb + (long)(b * 16 + h) * T * 128;
        const u16* plo = qbase + (long)(jlo * 64 + w * 16 + l15) * 128 + kl * 8;
        const u16* phi = qbase + (long)(jhi * 64 + w * 16 + l15) * 128 + kl * 8;
#pragma unroll
        for (int c = 0; c < 4; ++c) {
            qlo[c] = *reinterpret_cast<const bf16x8*>(plo + c * 32);
            qhi[c] = *reinterpret_cast<const bf16x8*>(phi + c * 32);
        }
    }

    f32x4 olo[8] = {}, ohi[8] = {};
    float llo = 0.f, lhi = 0.f;                     // per-lane partial sums (q = w*16+l15)

    const u16* kbase = kb + (long)(b * 4 + g) * T * 128;
    const u16* vbase = vtb + (long)(b * 4 + g) * 128 * T;
    const int c15 = tid & 15, c7 = tid & 7;

    auto STAGE = [&](int buf, int kt) {
#pragma unroll
        for (int r = 0; r < 4; ++r) {
            int idx = tid + r * 256;
            int key = idx >> 4;
            gld_lds16(kbase + (long)kt * 8192 + key * 128 + (c15 ^ (key & 7)) * 8,
                      &Ks[buf][idx * 8]);
        }
#pragma unroll
        for (int r = 0; r < 4; ++r) {
            int idx = tid + r * 256;
            int d = idx >> 3;
            gld_lds16(vbase + (long)d * T + kt * 64 + (c7 ^ (d & 7)) * 8,
                      &Vs[buf][idx * 8]);
        }
    };

    char* Psb = reinterpret_cast<char*>(Ps[w]);
    const int pswz = (l15 & 7) << 4;

    auto COMPUTE = [&](int buf, const bf16x8* qf, f32x4* oacc, float& lsum, bool diag) {
        const char* Kc = reinterpret_cast<const char*>(Ks[buf]);
        const char* Vc = reinterpret_cast<const char*>(Vs[buf]);
        f32x4 sacc[4] = {};   // S^T: sacc[kb4][jj] = S[key=kb4*16+kl*4+jj][q=w*16+l15]
        __builtin_amdgcn_s_setprio(1);
#pragma unroll
        for (int c = 0; c < 4; ++c) {
#pragma unroll
            for (int kb4 = 0; kb4 < 4; ++kb4) {
                int key = kb4 * 16 + l15;
                bf16x8 kf = *reinterpret_cast<const bf16x8*>(
                    Kc + key * 256 + ((c * 64 + kl * 16) ^ ((key & 7) << 4)));
                sacc[kb4] = __builtin_amdgcn_mfma_f32_16x16x32_bf16(kf, qf[c], sacc[kb4], 0, 0, 0);
            }
        }
        __builtin_amdgcn_s_setprio(0);

        if (diag) {
            int ql = w * 16 + l15;
#pragma unroll
            for (int kb4 = 0; kb4 < 4; ++kb4)
#pragma unroll
                for (int jj = 0; jj < 4; ++jj)
                    if (kb4 * 16 + kl * 4 + jj > ql) sacc[kb4][jj] = -1e30f;
        }

        float rs = 0.f;
#pragma unroll
        for (int kb4 = 0; kb4 < 4; ++kb4) {
            ushort4 pk;
            float p0 = __expf(sacc[kb4][0]), p1 = __expf(sacc[kb4][1]);
            float p2 = __expf(sacc[kb4][2]), p3 = __expf(sacc[kb4][3]);
            rs += (p0 + p1) + (p2 + p3);
            pk.x = f2bf(p0); pk.y = f2bf(p1); pk.z = f2bf(p2); pk.w = f2bf(p3);
            *reinterpret_cast<ushort4*>(Psb + ((l15 * 128 + kb4 * 32 + kl * 8) ^ pswz)) = pk;
        }
        lsum += rs;

        bf16x8 pa[2];
#pragma unroll
        for (int c = 0; c < 2; ++c)
            pa[c] = *reinterpret_cast<const bf16x8*>(Psb + ((l15 * 128 + c * 64 + kl * 16) ^ pswz));

        __builtin_amdgcn_s_setprio(1);
#pragma unroll
        for (int c = 0; c < 2; ++c) {
#pragma unroll
            for (int n = 0; n < 8; ++n) {
                int d = n * 16 + l15;
                bf16x8 vf = *reinterpret_cast<const bf16x8*>(
                    Vc + d * 128 + ((c * 64 + kl * 16) ^ ((d & 7) << 4)));
                oacc[n] = __builtin_amdgcn_mfma_f32_16x16x32_bf16(pa[c], vf, oacc[n], 0, 0, 0);
            }
        }
        __builtin_amdgcn_s_setprio(0);
    };

    STAGE(0, 0);
    VM_WAIT(0);
    __syncthreads();
    for (int kt = 0; kt <= jhi; ++kt) {
        int cur = kt & 1;
        if (kt < jhi) STAGE(cur ^ 1, kt + 1);   // overlap next-tile loads with compute
        COMPUTE(cur, qhi, ohi, lhi, kt == jhi);
        if (kt <= jlo) COMPUTE(cur, qlo, olo, llo, kt == jlo);
        VM_WAIT(0);
        __syncthreads();
    }

    auto EPILOG = [&](int j0, const f32x4* oacc, float lpart) {
        float lf = lpart;
        lf += __shfl_xor(lf, 16);
        lf += __shfl_xor(lf, 32);
        float inv = 1.f / lf;                 // valid for q = w*16 + l15
        float invj[4];
#pragma unroll
        for (int jj = 0; jj < 4; ++jj)
            invj[jj] = __shfl(inv, kl * 4 + jj);
#pragma unroll
        for (int jj = 0; jj < 4; ++jj) {
            int row = j0 * 64 + w * 16 + kl * 4 + jj;
            u16* op = ob + ((long)b * T + row) * 2048 + h * 128 + l15;
#pragma unroll
            for (int n = 0; n < 8; ++n) op[n * 16] = f2bf(oacc[n][jj] * invj[jj]);
        }
    };
    EPILOG(jlo, olo, llo);
    EPILOG(jhi, ohi, lhi);
}

// ---------- launch ----------
extern "C" void kernel_launch(void* const* d_in, const int* in_sizes, int n_in,
                              void* d_out, int out_size, void* d_ws, size_t ws_size,
                              hipStream_t stream) {
    (void)in_sizes; (void)n_in; (void)out_size; (void)ws_size;
    const float* x    = (const float*)d_in[0];
    const float* cosb = (const float*)d_in[1];
    const float* sinb = (const float*)d_in[2];
    const float* Wq   = (const float*)d_in[3];
    const float* bq   = (const float*)d_in[4];
    const float* Wkv  = (const float*)d_in[5];
    const float* bkv  = (const float*)d_in[6];
    const float* Wo   = (const float*)d_in[7];
    float* out = (float*)d_out;

    char* ws = (char*)d_ws;
    size_t off = 0;
    auto carve = [&](size_t bytes) -> char* {
        char* p = ws + off;
        off += (bytes + 255) & ~(size_t)255;
        return p;
    };
    u16* x_bf   = (u16*)carve(4096ull * 2048 * 2);
    u16* wq_bf  = (u16*)carve(2048ull * 2048 * 2);
    u16* wkv_bf = (u16*)carve(1024ull * 2048 * 2);
    u16* wo_bf  = (u16*)carve(2048ull * 2048 * 2);
    u16* q_buf  = (u16*)carve(32ull * 2048 * 128 * 2);
    u16* k_buf  = (u16*)carve(8ull * 2048 * 128 * 2);
    u16* vt_buf = (u16*)carve(8ull * 2048 * 128 * 2);
    u16* o_buf  = (u16*)carve(4096ull * 2048 * 2);

    // cast x, Wq, Wkv (Wo cast rides inside gemm1's idle CUs)
    cvt3<<<dim3(2048), dim3(256), 0, stream>>>(x, x_bf, 4096 * 2048 / 4,
                                               Wq, wq_bf, 2048 * 2048 / 4,
                                               Wkv, wkv_bf, 1024 * 2048 / 4);

    // QKV projection + fused rope/vt epilogue; blocks 192..255 cast Wo
    gemm_dp<256, 256, 1><<<dim3(256), dim3(512), 0, stream>>>(
        x_bf, wq_bf, wkv_bf, bq, bkv, (float*)nullptr, cosb, sinb,
        q_buf, k_buf, vt_buf, Wo, wo_bf, 4096, 3072, 2048, 2048, 12);

    attn_fwd<<<dim3(512), dim3(256), 0, stream>>>(q_buf, k_buf, vt_buf, o_buf);

    // O projection: M=4096, N=2048, K=2048 ; 128x128 tile, 512 blocks = 2/CU
    gemm_dp<128, 128, 0><<<dim3(512), dim3(256), 0, stream>>>(
        o_buf, wo_bf, wo_bf, (const float*)nullptr, (const float*)nullptr, out,
        (const float*)nullptr, (const float*)nullptr,
        (u16*)nullptr, (u16*)nullptr, (u16*)nullptr,
        (const float*)nullptr, (u16*)nullptr, 4096, 2048, 2048, 2048, 16);
}

// Round 17
// 182.143 us; speedup vs baseline: 1.0586x; 1.0586x over previous
//
#include <hip/hip_runtime.h>

// ---------- types ----------
typedef unsigned short u16;
typedef __bf16 bf16x8 __attribute__((ext_vector_type(8)));
typedef float f32x4 __attribute__((ext_vector_type(4)));
typedef unsigned short u16x8 __attribute__((ext_vector_type(8)));

#define VM_WAIT(N) asm volatile("s_waitcnt vmcnt(" #N ")" ::: "memory")

__device__ __forceinline__ u16 f2bf(float f) {
    union { float f; unsigned int u; } v; v.f = f;
    unsigned int r = v.u + 0x7fffu + ((v.u >> 16) & 1u);
    return (u16)(r >> 16);
}
__device__ __forceinline__ float bf2f(u16 h) {
    union { unsigned int u; float f; } v; v.u = ((unsigned int)h) << 16;
    return v.f;
}

__device__ __forceinline__ void gld_lds16(const void* g, void* l) {
    __builtin_amdgcn_global_load_lds(
        (const __attribute__((address_space(1))) void*)g,
        (__attribute__((address_space(3))) void*)l, 16, 0, 0);
}

// ---------- fused f32 -> bf16 cast of all 4 tensors ----------
__global__ __launch_bounds__(256) void cvt_all(const float* __restrict__ s0, u16* __restrict__ d0, int n0,
                                               const float* __restrict__ s1, u16* __restrict__ d1, int n1,
                                               const float* __restrict__ s2, u16* __restrict__ d2, int n2,
                                               const float* __restrict__ s3, u16* __restrict__ d3, int n3) {
    int total = n0 + n1 + n2 + n3;
    for (int i = blockIdx.x * 256 + threadIdx.x; i < total; i += gridDim.x * 256) {
        const float* s; u16* o; int j = i;
        if (j < n0) { s = s0; o = d0; }
        else if ((j -= n0) < n1) { s = s1; o = d1; }
        else if ((j -= n1) < n2) { s = s2; o = d2; }
        else { j -= n2; s = s3; o = d3; }
        float4 v = reinterpret_cast<const float4*>(s)[j];
        ushort4 u;
        u.x = f2bf(v.x); u.y = f2bf(v.y); u.z = f2bf(v.z); u.w = f2bf(v.w);
        reinterpret_cast<ushort4*>(o)[j] = u;
    }
}

// ---------- deep-pipelined GEMM, parametrized tile ----------
// BM=256 -> 512 thr, 2x4 waves ; BM=128 -> 256 thr, 2x2 waves (2 blocks/CU).
// MODE 0: C f32 out. MODE 1 (256x256, QKV): swapped mfma + fused rope/vt epilogue.
template <int BM, int BN, int MODE>
__global__ __launch_bounds__((BM == 256) ? 512 : 256, 2)
void gemm_dp(const u16* __restrict__ Amat,
             const u16* __restrict__ B1,
             const u16* __restrict__ B2,
             const float* __restrict__ bias1,
             const float* __restrict__ bias2,
             float* __restrict__ Cout,
             const float* __restrict__ cosb,
             const float* __restrict__ sinb,
             u16* __restrict__ qb,
             u16* __restrict__ kb,
             u16* __restrict__ vtb,
             int M, int N, int K, int NS, int nbn) {
    constexpr int THREADS = (BM == 256) ? 512 : 256;
    constexpr int WN = (BM == 256) ? 4 : 2;       // waves along N
    constexpr int WNS = (BM == 256) ? 2 : 1;      // log2(WN)
    constexpr int MF = BM / 32;                   // per-wave m-frags (BM/2/16)
    constexpr int NR = BN / (WN * 16);            // per-wave n-frags
    constexpr int RPI = THREADS / 4;              // rows per staging instr
    constexpr int SA = BM / RPI;
    constexpr int SB = BN / RPI;
    __shared__ __align__(16) u16 lds[2][(BM + BN) * 64];

    const int tid = threadIdx.x;
    const int lane = tid & 63;
    const int wid = tid >> 6;
    const int l15 = lane & 15, kl = lane >> 4;
    const int wm = wid >> WNS, wn = wid & (WN - 1);

    const int nwg = gridDim.x;
    const int cpx = nwg >> 3;
    const int bidr = blockIdx.x;
    const int swz = (bidr & 7) * cpx + (bidr >> 3);
    const int bm = swz / nbn, bn = swz % nbn;

    const int r0 = tid >> 2, c0 = tid & 3;

    const u16* agp[SA];
#pragma unroll
    for (int i = 0; i < SA; ++i) {
        int row = i * RPI + r0;
        agp[i] = Amat + (long)(bm * BM + row) * K + ((c0 ^ ((row >> 1) & 3)) * 8);
    }
    const u16* bgp[SB];
#pragma unroll
    for (int i = 0; i < SB; ++i) {
        int row = i * RPI + r0;
        int nrow = bn * BN + row;
        const u16* base = (nrow < NS) ? (B1 + (long)nrow * K) : (B2 + (long)(nrow - NS) * K);
        bgp[i] = base + ((c0 ^ ((row >> 1) & 3)) * 8);
    }

    auto STAGE_A = [&](int db, int kt, int kh) {
#pragma unroll
        for (int i = 0; i < SA; ++i)
            gld_lds16(agp[i] + kt * 64 + kh * 32,
                      &lds[db][kh * (BM * 32) + i * (RPI * 32) + tid * 8]);
    };
    auto STAGE_B = [&](int db, int kt, int kh) {
#pragma unroll
        for (int i = 0; i < SB; ++i)
            gld_lds16(bgp[i] + kt * 64 + kh * 32,
                      &lds[db][BM * 64 + kh * (BN * 32) + i * (RPI * 32) + tid * 8]);
    };

    f32x4 acc[MF][NR] = {};

#define PHASE(DB, KS, DOSTAGE, DOWAIT)                                                  \
    {                                                                                   \
        bf16x8 af[MF], bfr[NR];                                                         \
        _Pragma("unroll")                                                               \
        for (int i = 0; i < MF; ++i) {                                                  \
            int row = wm * (BM / 2) + i * 16 + l15;                                     \
            af[i] = *reinterpret_cast<const bf16x8*>(                                   \
                &lds[DB][(KS) * (BM * 32) + row * 32 + ((kl ^ ((row >> 1) & 3)) * 8)]); \
        }                                                                               \
        _Pragma("unroll")                                                               \
        for (int n = 0; n < NR; ++n) {                                                  \
            int brow = wn * (BN / WN) + n * 16 + l15;                                   \
            bfr[n] = *reinterpret_cast<const bf16x8*>(                                  \
                &lds[DB][BM * 64 + (KS) * (BN * 32) + brow * 32 +                       \
                         ((kl ^ ((brow >> 1) & 3)) * 8)]);                              \
        }                                                                               \
        DOSTAGE;                                                                        \
        DOWAIT;                                                                         \
        __builtin_amdgcn_s_barrier();                                                   \
        __builtin_amdgcn_s_setprio(1);                                                  \
        _Pragma("unroll")                                                               \
        for (int i = 0; i < MF; ++i)                                                    \
            _Pragma("unroll")                                                           \
            for (int n = 0; n < NR; ++n) {                                              \
                if constexpr (MODE == 1)                                                \
                    acc[i][n] = __builtin_amdgcn_mfma_f32_16x16x32_bf16(                \
                        bfr[n], af[i], acc[i][n], 0, 0, 0);                             \
                else                                                                    \
                    acc[i][n] = __builtin_amdgcn_mfma_f32_16x16x32_bf16(                \
                        af[i], bfr[n], acc[i][n], 0, 0, 0);                             \
            }                                                                           \
        __builtin_amdgcn_s_setprio(0);                                                  \
    }

    STAGE_A(0, 0, 0); STAGE_B(0, 0, 0); STAGE_A(0, 0, 1); STAGE_B(0, 0, 1);
    VM_WAIT(4);
    __builtin_amdgcn_s_barrier();

    const int NT = K >> 6;
    for (int t = 0; t < NT; ++t) {
        const int db = t & 1;
        const bool pre = (t + 1) < NT;
        const int kt1 = t + 1;
        PHASE(db, 0, { if (pre) { STAGE_A(db ^ 1, kt1, 0); STAGE_B(db ^ 1, kt1, 0); } },
              { if (pre) VM_WAIT(4); else VM_WAIT(0); });
        PHASE(db, 1, { if (pre) { STAGE_A(db ^ 1, kt1, 1); STAGE_B(db ^ 1, kt1, 1); } },
              { if (pre) VM_WAIT(4); else VM_WAIT(0); });
    }
#undef PHASE

    if constexpr (MODE == 0) {
#pragma unroll
        for (int n = 0; n < NR; ++n) {
            int col = bn * BN + wn * (BN / WN) + n * 16 + l15;
            float bv = 0.f;
            if (bias1) bv = (col < NS) ? bias1[col] : bias2[col - NS];
#pragma unroll
            for (int m = 0; m < MF; ++m) {
                int row = bm * BM + wm * (BM / 2) + m * 16 + kl * 4;
                float* cp = Cout + (long)row * N + col;
#pragma unroll
                for (int j = 0; j < 4; ++j) cp[(long)j * N] = acc[m][n][j] + bv;
            }
        }
    } else {
        // ---- fused QKV epilogue (BM=256/512thr only) ----
        const float SCALE = 0.08838834764831845f; // 1/sqrt(128)
        const int T = 2048;
        __syncthreads();
        char* otb = reinterpret_cast<char*>(lds);
#pragma unroll
        for (int n = 0; n < NR; ++n) {
            int cbase = wn * 64 + n * 16 + kl * 4;
            int col = bn * BN + cbase;
            const float* bsrc = (col < NS) ? (bias1 + col) : (bias2 + col - NS);
            float4 bv4 = *reinterpret_cast<const float4*>(bsrc);
#pragma unroll
            for (int i = 0; i < MF; ++i) {
                int lrow = wm * 128 + i * 16 + l15;
                ushort4 pk;
                pk.x = f2bf(acc[i][n][0] + bv4.x);
                pk.y = f2bf(acc[i][n][1] + bv4.y);
                pk.z = f2bf(acc[i][n][2] + bv4.z);
                pk.w = f2bf(acc[i][n][3] + bv4.w);
                int byteoff = lrow * 512 + ((((cbase >> 3) ^ (lrow & 31)) << 4) +
                                            ((cbase & 7) << 1));
                *reinterpret_cast<ushort4*>(otb + byteoff) = pk;
            }
        }
        __syncthreads();

        const int R0 = bm * BM;
        const int bb = R0 >> 11;
        const int t0 = R0 & 2047;

        if (bn < 8) {
            int r = tid >> 1, side = tid & 1;
            int h = bn * 2 + side, tt = t0 + r;
            const float* cr = cosb + tt * 128;
            const float* sr = sinb + tt * 128;
            const char* srcr = otb + r * 512;
            int rx = r & 31;
            u16* dst = qb + ((long)(bb * 16 + h) * T + tt) * 128;
#pragma unroll
            for (int d0 = 0; d0 < 64; d0 += 8) {
                u16x8 a = *reinterpret_cast<const u16x8*>(
                    srcr + (((side * 16 + (d0 >> 3)) ^ rx) << 4));
                u16x8 bvv = *reinterpret_cast<const u16x8*>(
                    srcr + (((side * 16 + 8 + (d0 >> 3)) ^ rx) << 4));
                u16x8 o1, o2;
#pragma unroll
                for (int j = 0; j < 8; ++j) {
                    float q1 = bf2f(a[j]), q2 = bf2f(bvv[j]);
                    o1[j] = f2bf((q1 * cr[d0 + j] - q2 * sr[d0 + j]) * SCALE);
                    o2[j] = f2bf((q2 * cr[64 + d0 + j] + q1 * sr[64 + d0 + j]) * SCALE);
                }
                *reinterpret_cast<u16x8*>(dst + d0) = o1;
                *reinterpret_cast<u16x8*>(dst + 64 + d0) = o2;
            }
        } else if (bn < 10) {
            int r = tid >> 1, side = tid & 1;
            int g = (bn - 8) * 2 + side, tt = t0 + r;
            const float* cr = cosb + tt * 128;
            const float* sr = sinb + tt * 128;
            const char* srcr = otb + r * 512;
            int rx = r & 31;
            u16* dst = kb + ((long)(bb * 4 + g) * T + tt) * 128;
#pragma unroll
            for (int d0 = 0; d0 < 64; d0 += 8) {
                u16x8 a = *reinterpret_cast<const u16x8*>(
                    srcr + (((side * 16 + (d0 >> 3)) ^ rx) << 4));
                u16x8 bvv = *reinterpret_cast<const u16x8*>(
                    srcr + (((side * 16 + 8 + (d0 >> 3)) ^ rx) << 4));
                u16x8 o1, o2;
#pragma unroll
                for (int j = 0; j < 8; ++j) {
                    float k1 = bf2f(a[j]), k2 = bf2f(bvv[j]);
                    o1[j] = f2bf(k1 * cr[d0 + j] - k2 * sr[d0 + j]);
                    o2[j] = f2bf(k2 * cr[64 + d0 + j] + k1 * sr[64 + d0 + j]);
                }
                *reinterpret_cast<u16x8*>(dst + d0) = o1;
                *reinterpret_cast<u16x8*>(dst + 64 + d0) = o2;
            }
        } else {
            int cl = tid >> 1, th = tid & 1;
            int side = cl >> 7, d = cl & 127;
            int g = (bn - 10) * 2 + side;
            u16* dst = vtb + ((long)(bb * 4 + g) * 128 + d) * T + t0 + th * 128;
            int cch = cl >> 3, coff = (cl & 7) << 1;
#pragma unroll
            for (int i0 = 0; i0 < 128; i0 += 8) {
                u16 tmp[8];
#pragma unroll
                for (int i = 0; i < 8; ++i) {
                    int row = th * 128 + i0 + i;
                    tmp[i] = *reinterpret_cast<const u16*>(
                        otb + row * 512 + (((cch ^ (row & 31)) << 4) + coff));
                }
                *reinterpret_cast<uint4*>(dst + i0) = *reinterpret_cast<const uint4*>(tmp);
            }
        }
    }
}

// ---------- flash attention, causal GQA (R8 structure + XCD-clustered bid) ----------
__global__ __launch_bounds__(256, 2) void attn_fwd(const u16* __restrict__ qb,
                                                   const u16* __restrict__ kb,
                                                   const u16* __restrict__ vtb,
                                                   u16* __restrict__ ob) {
    const int T = 2048;
    __shared__ __align__(16) u16 Ks[2][64 * 128];   // [buf][key][d], XOR-swizzled
    __shared__ __align__(16) u16 Vs[2][128 * 64];   // [buf][d][key], XOR-swizzled
    __shared__ __align__(16) u16 Ps[4][16 * 64];    // per-wave P^ [q][key], XOR-swizzled

    const int tid = threadIdx.x;
    const int lane = tid & 63;
    const int w = tid >> 6;
    const int l15 = lane & 15, kl = lane >> 4;
    const int bid = blockIdx.x;                     // 512 ; bid&7 == b*4+g -> one (b,g)/XCD
    const int g = bid & 3;
    const int b = (bid >> 2) & 1;
    const int jp = (bid >> 3) & 15;
    const int hh = (bid >> 7) & 3;
    const int h = g * 4 + hh;
    const int jlo = jp, jhi = 31 - jp;              // paired Q-tiles: work = 33 everywhere

    bf16x8 qlo[4], qhi[4];
    {
        const u16* qbase = qb + (long)(b * 16 + h) * T * 128;
        const u16* plo = qbase + (long)(jlo * 64 + w * 16 + l15) * 128 + kl * 8;
        const u16* phi = qbase + (long)(jhi * 64 + w * 16 + l15) * 128 + kl * 8;
#pragma unroll
        for (int c = 0; c < 4; ++c) {
            qlo[c] = *reinterpret_cast<const bf16x8*>(plo + c * 32);
            qhi[c] = *reinterpret_cast<const bf16x8*>(phi + c * 32);
        }
    }

    f32x4 olo[8] = {}, ohi[8] = {};
    float llo = 0.f, lhi = 0.f;                     // per-lane partial sums (q = w*16+l15)

    const u16* kbase = kb + (long)(b * 4 + g) * T * 128;
    const u16* vbase = vtb + (long)(b * 4 + g) * 128 * T;
    const int c15 = tid & 15, c7 = tid & 7;

    auto STAGE = [&](int buf, int kt) {
#pragma unroll
        for (int r = 0; r < 4; ++r) {
            int idx = tid + r * 256;
            int key = idx >> 4;
            gld_lds16(kbase + (long)kt * 8192 + key * 128 + (c15 ^ (key & 7)) * 8,
                      &Ks[buf][idx * 8]);
        }
#pragma unroll
        for (int r = 0; r < 4; ++r) {
            int idx = tid + r * 256;
            int d = idx >> 3;
            gld_lds16(vbase + (long)d * T + kt * 64 + (c7 ^ (d & 7)) * 8,
                      &Vs[buf][idx * 8]);
        }
    };

    char* Psb = reinterpret_cast<char*>(Ps[w]);
    const int pswz = (l15 & 7) << 4;

    auto COMPUTE = [&](int buf, const bf16x8* qf, f32x4* oacc, float& lsum, bool diag) {
        const char* Kc = reinterpret_cast<const char*>(Ks[buf]);
        const char* Vc = reinterpret_cast<const char*>(Vs[buf]);
        f32x4 sacc[4] = {};   // S^T: sacc[kb4][jj] = S[key=kb4*16+kl*4+jj][q=w*16+l15]
        __builtin_amdgcn_s_setprio(1);
#pragma unroll
        for (int c = 0; c < 4; ++c) {
#pragma unroll
            for (int kb4 = 0; kb4 < 4; ++kb4) {
                int key = kb4 * 16 + l15;
                bf16x8 kf = *reinterpret_cast<const bf16x8*>(
                    Kc + key * 256 + ((c * 64 + kl * 16) ^ ((key & 7) << 4)));
                sacc[kb4] = __builtin_amdgcn_mfma_f32_16x16x32_bf16(kf, qf[c], sacc[kb4], 0, 0, 0);
            }
        }
        __builtin_amdgcn_s_setprio(0);

        if (diag) {
            int ql = w * 16 + l15;
#pragma unroll
            for (int kb4 = 0; kb4 < 4; ++kb4)
#pragma unroll
                for (int jj = 0; jj < 4; ++jj)
                    if (kb4 * 16 + kl * 4 + jj > ql) sacc[kb4][jj] = -1e30f;
        }

        float rs = 0.f;
#pragma unroll
        for (int kb4 = 0; kb4 < 4; ++kb4) {
            ushort4 pk;
            float p0 = __expf(sacc[kb4][0]), p1 = __expf(sacc[kb4][1]);
            float p2 = __expf(sacc[kb4][2]), p3 = __expf(sacc[kb4][3]);
            rs += (p0 + p1) + (p2 + p3);
            pk.x = f2bf(p0); pk.y = f2bf(p1); pk.z = f2bf(p2); pk.w = f2bf(p3);
            *reinterpret_cast<ushort4*>(Psb + ((l15 * 128 + kb4 * 32 + kl * 8) ^ pswz)) = pk;
        }
        lsum += rs;

        bf16x8 pa[2];
#pragma unroll
        for (int c = 0; c < 2; ++c)
            pa[c] = *reinterpret_cast<const bf16x8*>(Psb + ((l15 * 128 + c * 64 + kl * 16) ^ pswz));

        __builtin_amdgcn_s_setprio(1);
#pragma unroll
        for (int c = 0; c < 2; ++c) {
#pragma unroll
            for (int n = 0; n < 8; ++n) {
                int d = n * 16 + l15;
                bf16x8 vf = *reinterpret_cast<const bf16x8*>(
                    Vc + d * 128 + ((c * 64 + kl * 16) ^ ((d & 7) << 4)));
                oacc[n] = __builtin_amdgcn_mfma_f32_16x16x32_bf16(pa[c], vf, oacc[n], 0, 0, 0);
            }
        }
        __builtin_amdgcn_s_setprio(0);
    };

    STAGE(0, 0);
    VM_WAIT(0);
    __syncthreads();
    for (int kt = 0; kt <= jhi; ++kt) {
        int cur = kt & 1;
        if (kt < jhi) STAGE(cur ^ 1, kt + 1);   // overlap next-tile loads with compute
        COMPUTE(cur, qhi, ohi, lhi, kt == jhi);
        if (kt <= jlo) COMPUTE(cur, qlo, olo, llo, kt == jlo);
        VM_WAIT(0);
        __syncthreads();
    }

    auto EPILOG = [&](int j0, const f32x4* oacc, float lpart) {
        float lf = lpart;
        lf += __shfl_xor(lf, 16);
        lf += __shfl_xor(lf, 32);
        float inv = 1.f / lf;                 // valid for q = w*16 + l15
        float invj[4];
#pragma unroll
        for (int jj = 0; jj < 4; ++jj)
            invj[jj] = __shfl(inv, kl * 4 + jj);
#pragma unroll
        for (int jj = 0; jj < 4; ++jj) {
            int row = j0 * 64 + w * 16 + kl * 4 + jj;
            u16* op = ob + ((long)b * T + row) * 2048 + h * 128 + l15;
#pragma unroll
            for (int n = 0; n < 8; ++n) op[n * 16] = f2bf(oacc[n][jj] * invj[jj]);
        }
    };
    EPILOG(jlo, olo, llo);
    EPILOG(jhi, ohi, lhi);
}

// ---------- launch ----------
extern "C" void kernel_launch(void* const* d_in, const int* in_sizes, int n_in,
                              void* d_out, int out_size, void* d_ws, size_t ws_size,
                              hipStream_t stream) {
    (void)in_sizes; (void)n_in; (void)out_size; (void)ws_size;
    const float* x    = (const float*)d_in[0];
    const float* cosb = (const float*)d_in[1];
    const float* sinb = (const float*)d_in[2];
    const float* Wq   = (const float*)d_in[3];
    const float* bq   = (const float*)d_in[4];
    const float* Wkv  = (const float*)d_in[5];
    const float* bkv  = (const float*)d_in[6];
    const float* Wo   = (const float*)d_in[7];
    float* out = (float*)d_out;

    char* ws = (char*)d_ws;
    size_t off = 0;
    auto carve = [&](size_t bytes) -> char* {
        char* p = ws + off;
        off += (bytes + 255) & ~(size_t)255;
        return p;
    };
    u16* x_bf   = (u16*)carve(4096ull * 2048 * 2);
    u16* wq_bf  = (u16*)carve(2048ull * 2048 * 2);
    u16* wkv_bf = (u16*)carve(1024ull * 2048 * 2);
    u16* wo_bf  = (u16*)carve(2048ull * 2048 * 2);
    u16* q_buf  = (u16*)carve(32ull * 2048 * 128 * 2);
    u16* k_buf  = (u16*)carve(8ull * 2048 * 128 * 2);
    u16* vt_buf = (u16*)carve(8ull * 2048 * 128 * 2);
    u16* o_buf  = (u16*)carve(4096ull * 2048 * 2);

    // single fused cast launch (x, Wq, Wkv, Wo)
    cvt_all<<<dim3(2048), dim3(256), 0, stream>>>(x, x_bf, 4096 * 2048 / 4,
                                                  Wq, wq_bf, 2048 * 2048 / 4,
                                                  Wkv, wkv_bf, 1024 * 2048 / 4,
                                                  Wo, wo_bf, 2048 * 2048 / 4);

    // QKV projection + fused rope/vt epilogue: M=4096, N=3072, K=2048
    gemm_dp<256, 256, 1><<<dim3(192), dim3(512), 0, stream>>>(
        x_bf, wq_bf, wkv_bf, bq, bkv, (float*)nullptr, cosb, sinb,
        q_buf, k_buf, vt_buf, 4096, 3072, 2048, 2048, 12);

    attn_fwd<<<dim3(512), dim3(256), 0, stream>>>(q_buf, k_buf, vt_buf, o_buf);

    // O projection: M=4096, N=2048, K=2048 ; 128x128 tile, 512 blocks = 2/CU
    gemm_dp<128, 128, 0><<<dim3(512), dim3(256), 0, stream>>>(
        o_buf, wo_bf, wo_bf, (const float*)nullptr, (const float*)nullptr, out,
        (const float*)nullptr, (const float*)nullptr,
        (u16*)nullptr, (u16*)nullptr, (u16*)nullptr, 4096, 2048, 2048, 2048, 16);
}